// Round 2
// 1015.193 us; speedup vs baseline: 1.0132x; 1.0132x over previous
//
#include <hip/hip_runtime.h>
#include <hip/hip_bf16.h>

typedef __bf16 bf16_t;
typedef bf16_t bf16x8 __attribute__((ext_vector_type(8)));
typedef float  floatx4 __attribute__((ext_vector_type(4)));

constexpr int Bb = 4, Hh = 16, Nn = 2048, Dd = 64;
constexpr int BM = 128;  // queries per workgroup (8 waves)
constexpr int BN = 64;   // keys per tile
constexpr int WM = 16;   // queries per wave
constexpr float SCALE = 0.125f;                      // D^-0.5
constexpr float NEG   = -3.4028234663852886e38f;     // -FLT_MAX, matches reference

// Flash attention, bf16 MFMA (16x16x32), fp32 softmax state.
// BM=128 / 512 threads: 32 KiB LDS/block -> up to 4 blocks/CU * 8 waves =
// 32 waves/CU if VGPR<=64. Grid = 1024 = exactly 4 blocks/CU, no tail.
// launch_bounds min-waves kept at 4 so the allocator is not FORCED to spill;
// with ~48-60 VGPRs it should reach 8 waves/SIMD naturally.
// LDS K/V tiles are stored pre-swizzled in MFMA B-fragment chunk order so each
// wave's fragment load is one lane-contiguous ds_read_b128 (zero conflicts).
__global__ __launch_bounds__(512, 4)
void attn_fwd(const float* __restrict__ qg,
              const float* __restrict__ kg,
              const float* __restrict__ vg,
              const void*  __restrict__ maskg,
              const float* __restrict__ biasg,
              float* __restrict__ outg)
{
    // chunk = ((blk*2+kk)*64 + quad*16 + n); element j <-> K[key=blk*16+n][d=kk*32+quad*8+j]
    __shared__ bf16x8 k_lds[512];
    // chunk = ((kk*4+nblk)*64 + quad*16 + n); element j <-> V[key=kk*32+quad*8+j][d=nblk*16+n]
    __shared__ bf16x8 v_lds[512];
    // per-wave P: chunk = kk*64 + quad*16 + m; element j <-> P[m][key=kk*32+quad*8+j]
    __shared__ bf16x8 p_lds[8][128];

    const int tid  = threadIdx.x;
    const int wave = tid >> 6;
    const int lane = tid & 63;
    const int ln   = lane & 15;   // n (or m) within 16
    const int lq   = lane >> 4;   // quad

    const int id = blockIdx.x;    // b fastest: 4 batches sharing a bias slice run adjacently
    const int b  = id & 3;
    const int h  = (id >> 2) & 15;
    const int mt = id >> 6;       // 0..15

    // ---- mask dtype probe (wave-uniform branch) ----
    // int32 0/1 data always passes; uint8 data (90% ones) passes with p ~ 1e-48.
    const int probe = ((const int*)maskg)[lane];
    const bool mask_i32 = __all(probe == 0 || probe == 1);
    const int*           mi = (const int*)maskg;
    const unsigned char* mb = (const unsigned char*)maskg;

    const size_t head  = (size_t)(b*Hh + h) * Nn * Dd;
    const int    qbase = mt*BM + wave*WM;

    // ---- Q A-fragments straight from global (one-time) ----
    bf16x8 qa[2];
    {
        const float* qp = qg + head + (size_t)(qbase + ln)*Dd + lq*8;
        #pragma unroll
        for (int kk = 0; kk < 2; ++kk) {
            float4 f0 = *(const float4*)(qp + kk*32);
            float4 f1 = *(const float4*)(qp + kk*32 + 4);
            bf16x8 a;
            a[0]=(bf16_t)f0.x; a[1]=(bf16_t)f0.y; a[2]=(bf16_t)f0.z; a[3]=(bf16_t)f0.w;
            a[4]=(bf16_t)f1.x; a[5]=(bf16_t)f1.y; a[6]=(bf16_t)f1.z; a[7]=(bf16_t)f1.w;
            qa[kk] = a;
        }
    }

    floatx4 o_acc[4];
    #pragma unroll
    for (int i = 0; i < 4; ++i) o_acc[i] = (floatx4){0.f,0.f,0.f,0.f};
    float mx[4], lsum[4];
    #pragma unroll
    for (int r = 0; r < 4; ++r) { mx[r] = -__builtin_inff(); lsum[r] = 0.f; }

    // staging decomposition (512 threads cover 64 keys x 64 d; 8 floats/thread each for K and V)
    const int skey = tid >> 3;
    const int sd0  = (tid & 7) * 8;
    const int sblk = skey >> 4, sn = skey & 15;          // K-side
    const int kkg  = sd0 >> 5,  qg2 = (sd0 >> 3) & 3;    // K chunk coords (one chunk/thread)
    const int vkk  = skey >> 5, vq = (skey >> 3) & 3, vj = skey & 7;  // V-side
    const int vnb  = sd0 >> 4;                           // d-block constant per thread
    bf16_t* vl = (bf16_t*)v_lds;
    bf16_t* pl = (bf16_t*)p_lds[wave];

    for (int kt = 0; kt < Nn/BN; ++kt) {
        __syncthreads();   // previous tile's v_lds/k_lds reads complete
        {
            const float* kp = kg + head + (size_t)(kt*BN + skey)*Dd + sd0;
            const float* vp = vg + head + (size_t)(kt*BN + skey)*Dd + sd0;
            float4 k0 = *(const float4*)(kp);
            float4 k1 = *(const float4*)(kp + 4);
            float4 v0 = *(const float4*)(vp);
            float4 v1 = *(const float4*)(vp + 4);
            bf16x8 c;
            c[0]=(bf16_t)k0.x; c[1]=(bf16_t)k0.y; c[2]=(bf16_t)k0.z; c[3]=(bf16_t)k0.w;
            c[4]=(bf16_t)k1.x; c[5]=(bf16_t)k1.y; c[6]=(bf16_t)k1.z; c[7]=(bf16_t)k1.w;
            k_lds[(sblk*2 + kkg)*64 + qg2*16 + sn] = c;   // one b128 write
            float vvv[8];
            *(float4*)(vvv)   = v0;
            *(float4*)(vvv+4) = v1;
            #pragma unroll
            for (int t = 0; t < 8; ++t) {                 // V: transposed scatter (b16 writes)
                const int nn2 = (sd0 & 8) + t;            // (sd0+t) & 15
                vl[(((vkk*4 + vnb)*64 + vq*16 + nn2) << 3) | vj] = (bf16_t)vvv[t];
            }
        }
        __syncthreads();

        // ---- S = Q K^T  (16m x 64keys per wave) ----
        floatx4 s_acc[4];
        #pragma unroll
        for (int i = 0; i < 4; ++i) s_acc[i] = (floatx4){0.f,0.f,0.f,0.f};
        #pragma unroll
        for (int blk = 0; blk < 4; ++blk)
            #pragma unroll
            for (int kk = 0; kk < 2; ++kk)
                s_acc[blk] = __builtin_amdgcn_mfma_f32_16x16x32_bf16(
                    qa[kk], k_lds[(blk*2+kk)*64 + lane], s_acc[blk], 0, 0, 0);

        // ---- scale + bias + mask, online softmax ----
        float sv[4][4], rmax[4];
        const size_t col0 = (size_t)kt*BN + ln;
        #pragma unroll
        for (int r = 0; r < 4; ++r) {
            const int m = qbase + lq*4 + r;
            const size_t brow = ((size_t)h*Nn + m)*Nn + col0;
            const size_t mrow = ((size_t)b*Nn + m)*Nn + col0;
            rmax[r] = NEG;
            #pragma unroll
            for (int blk = 0; blk < 4; ++blk) {
                float val = s_acc[blk][r]*SCALE + biasg[brow + blk*16];
                const bool ok = mask_i32 ? (mi[mrow + blk*16] != 0)
                                         : (mb[mrow + blk*16] != 0);
                val = ok ? val : NEG;
                sv[r][blk] = val;
                rmax[r] = fmaxf(rmax[r], val);
            }
        }
        #pragma unroll
        for (int off = 1; off < 16; off <<= 1)
            #pragma unroll
            for (int r = 0; r < 4; ++r)
                rmax[r] = fmaxf(rmax[r], __shfl_xor(rmax[r], off, 64));

        float alph[4], rsum[4];
        bf16_t pb[4][4];
        #pragma unroll
        for (int r = 0; r < 4; ++r) {
            const float mnew = fmaxf(mx[r], rmax[r]);
            alph[r] = __expf(mx[r] - mnew);
            mx[r] = mnew;
            float s = 0.f;
            #pragma unroll
            for (int blk = 0; blk < 4; ++blk) {
                const bf16_t p = (bf16_t)__expf(sv[r][blk] - mnew);
                pb[r][blk] = p;
                s += (float)p;   // sum the bf16-rounded p: num/denom stay consistent
            }
            rsum[r] = s;
        }
        #pragma unroll
        for (int off = 1; off < 16; off <<= 1)
            #pragma unroll
            for (int r = 0; r < 4; ++r)
                rsum[r] += __shfl_xor(rsum[r], off, 64);
        #pragma unroll
        for (int r = 0; r < 4; ++r) {
            lsum[r] = lsum[r]*alph[r] + rsum[r];
            #pragma unroll
            for (int nb = 0; nb < 4; ++nb)
                o_acc[nb][r] *= alph[r];
        }

        // ---- P -> LDS (C-layout -> A-layout round trip; p_lds is per-wave, so
        //      no barrier needed: compiler inserts the lgkmcnt wait for the
        //      same-wave write->read dependency) ----
        #pragma unroll
        for (int r = 0; r < 4; ++r) {
            const int m = lq*4 + r;
            #pragma unroll
            for (int blk = 0; blk < 4; ++blk) {
                const int key = blk*16 + ln;
                const int kk2 = key >> 5, q2 = (key >> 3) & 3, j2 = key & 7;
                pl[((kk2*64 + q2*16 + m) << 3) | j2] = pb[r][blk];
            }
        }

        // ---- O += P V ----
        #pragma unroll
        for (int kk = 0; kk < 2; ++kk) {
            const bf16x8 pa = p_lds[wave][kk*64 + lane];
            #pragma unroll
            for (int nb = 0; nb < 4; ++nb)
                o_acc[nb] = __builtin_amdgcn_mfma_f32_16x16x32_bf16(
                    pa, v_lds[(kk*4+nb)*64 + lane], o_acc[nb], 0, 0, 0);
        }
    }

    // ---- epilogue: O / l ----
    #pragma unroll
    for (int r = 0; r < 4; ++r) {
        const int m = qbase + lq*4 + r;
        const float inv = 1.f / lsum[r];
        float* op = outg + head + (size_t)m*Dd + ln;
        #pragma unroll
        for (int nb = 0; nb < 4; ++nb)
            op[nb*16] = o_acc[nb][r] * inv;
    }
}

extern "C" void kernel_launch(void* const* d_in, const int* in_sizes, int n_in,
                              void* d_out, int out_size, void* d_ws, size_t ws_size,
                              hipStream_t stream) {
    const float* q    = (const float*)d_in[0];
    const float* k    = (const float*)d_in[1];
    const float* v    = (const float*)d_in[2];
    const void*  mask = d_in[3];
    const float* bias = (const float*)d_in[4];
    float* out = (float*)d_out;
    (void)in_sizes; (void)n_in; (void)out_size; (void)d_ws; (void)ws_size;

    const int grid = Bb * Hh * (Nn / BM);   // 1024
    attn_fwd<<<grid, 512, 0, stream>>>(q, k, v, mask, bias, out);
}